// Round 17
// baseline (204.064 us; speedup 1.0000x reference)
//
#include <hip/hip_runtime.h>
#include <math.h>

#define D 256
#define B 16
#define L 8
#define N 128

static constexpr float LAMBDA_ASYNC = 0.08f;
static constexpr float LAMBDA_TAU   = 0.12f;

// ws layout (floats):
//   acct[4096]   @ 0      (pre-scaled vin [d][b]; xt for l==0)
//   colsum[256]  @ 4096
//   meta[16]     @ 4352
//   fired[128]   @ 4368
//   slab @ 4496:  NQ=2: [n][dh][4096] raw partials (4.2 MB)
//                 NQ=1: [n][4096] tanh'd tiles (2.1 MB, R15 path)
// Reduce is BRANCHLESS (R14 law: conditional loads serialize cross-XCD
// misses; mask with fired[n] multiply instead).

#define OFF_COLSUM 4096
#define OFF_META   4352
#define OFF_FIRED  4368
#define OFF_SLAB   4496

// X[b][d] -> xt[d][b]; colsum0[d] = sum_b X[b][d]   (R9-proven)
__global__ __launch_bounds__(256) void transpose_kernel(
    const float* __restrict__ X, float* __restrict__ xt,
    float* __restrict__ colsum) {
    const int d = threadIdx.x;
    float cs = 0.0f;
    #pragma unroll
    for (int b = 0; b < B; ++b) {
        const float v = X[b * D + d];
        xt[d * 16 + b] = v;
        cs += v;
    }
    colsum[d] = cs;
}

// ======== NQ=2 split path: 512 blocks = (n, d-half, e-half), 256 thr ========
// Wave w owns d-rows [dh*128 + w*32, +32); lane owns e-pair e0+lane*2+{0,1}.
// Per row: 1 global_load_dwordx2 (W) + 4 broadcast ds_read_b128 + 32 FMA —
// EXACT R15 loop body; block W 64 KB, block DS 512 instrs (both halved).
__global__ __launch_bounds__(256) void layer_split(
    const float* __restrict__ Wl, const float* __restrict__ Sl,
    const float* __restrict__ rhol, const float* __restrict__ boostl,
    const int*  __restrict__ tb,
    const float* __restrict__ vin_src,    // [d][b] pre-scaled (xt for l==0)
    const float* __restrict__ colsum,     // [256]
    const float* __restrict__ meta_prev,  // null for l==0
    float* __restrict__ slab,             // [n][2][4096] raw partials
    float* __restrict__ fired_cur,
    float depth, int is_first)
{
    __shared__ float vin[128 * 16];      // d-half slice, 8 KB
    __shared__ float red[2 * 64 * 33];   // 2-slot cross-wave partials, 17 KB
    __shared__ float sh[4];

    const int t    = threadIdx.x;
    const int w    = t >> 6;
    const int lane = t & 63;
    const int n    = blockIdx.x >> 2;
    const int dh   = (blockIdx.x >> 1) & 1;
    const int eh   = blockIdx.x & 1;
    const int e0   = eh * 128;
    const int d0   = dh * 128;

    // ---- firing preamble from global colsum (full-d dot) — before staging
    float part = colsum[t] * Sl[n * D + t];
    #pragma unroll
    for (int o = 32; o > 0; o >>= 1) part += __shfl_down(part, o);
    if (lane == 0) sh[w] = part;
    __syncthreads();
    {
        const bool has_input = is_first ? true : (meta_prev[0] > 0.0f);
        const float sdot = (sh[0] + sh[1] + sh[2] + sh[3]) * (1.0f / 16.0f);
        const float tau  = 0.5f * expf(LAMBDA_TAU * (depth - (float)tb[0]));
        const bool fired = (rhol[n] + sdot + boostl[n] >= tau) && has_input;
        if ((blockIdx.x & 3) == 0 && t == 0) fired_cur[n] = fired ? 1.0f : 0.0f;
        if (!fired) return;
    }

    // ---- stage this d-half of vin (8 KB vector copy)
    {
        const float4* s4 = (const float4*)vin_src + (size_t)d0 * 4;
        ((float4*)vin)[t * 2 + 0] = s4[t * 2 + 0];
        ((float4*)vin)[t * 2 + 1] = s4[t * 2 + 1];
    }
    __syncthreads();

    // ---- main loop: 32 local d-rows for this wave (R15's proven body)
    const float* wp = Wl + ((size_t)n * D + (size_t)(d0 + w * 32)) * D + (e0 + lane * 2);
    const int dbase = w * 32;

    float accA[16], accB[16];
    #pragma unroll
    for (int b = 0; b < 16; ++b) { accA[b] = 0.0f; accB[b] = 0.0f; }

    #pragma unroll
    for (int j = 0; j < 32; j += 4) {
        float2 wv[4];
        #pragma unroll
        for (int i = 0; i < 4; ++i)
            wv[i] = *(const float2*)(wp + (size_t)(j + i) * 256);
        #pragma unroll
        for (int i = 0; i < 4; ++i) {
            const float* vr = &vin[(dbase + j + i) * 16];
            const float4 v0 = *(const float4*)(vr + 0);
            const float4 v1 = *(const float4*)(vr + 4);
            const float4 v2 = *(const float4*)(vr + 8);
            const float4 v3 = *(const float4*)(vr + 12);
            const float wx = wv[i].x, wy = wv[i].y;
            accA[ 0] = fmaf(wx, v0.x, accA[ 0]); accB[ 0] = fmaf(wy, v0.x, accB[ 0]);
            accA[ 1] = fmaf(wx, v0.y, accA[ 1]); accB[ 1] = fmaf(wy, v0.y, accB[ 1]);
            accA[ 2] = fmaf(wx, v0.z, accA[ 2]); accB[ 2] = fmaf(wy, v0.z, accB[ 2]);
            accA[ 3] = fmaf(wx, v0.w, accA[ 3]); accB[ 3] = fmaf(wy, v0.w, accB[ 3]);
            accA[ 4] = fmaf(wx, v1.x, accA[ 4]); accB[ 4] = fmaf(wy, v1.x, accB[ 4]);
            accA[ 5] = fmaf(wx, v1.y, accA[ 5]); accB[ 5] = fmaf(wy, v1.y, accB[ 5]);
            accA[ 6] = fmaf(wx, v1.z, accA[ 6]); accB[ 6] = fmaf(wy, v1.z, accB[ 6]);
            accA[ 7] = fmaf(wx, v1.w, accA[ 7]); accB[ 7] = fmaf(wy, v1.w, accB[ 7]);
            accA[ 8] = fmaf(wx, v2.x, accA[ 8]); accB[ 8] = fmaf(wy, v2.x, accB[ 8]);
            accA[ 9] = fmaf(wx, v2.y, accA[ 9]); accB[ 9] = fmaf(wy, v2.y, accB[ 9]);
            accA[10] = fmaf(wx, v2.z, accA[10]); accB[10] = fmaf(wy, v2.z, accB[10]);
            accA[11] = fmaf(wx, v2.w, accA[11]); accB[11] = fmaf(wy, v2.w, accB[11]);
            accA[12] = fmaf(wx, v3.x, accA[12]); accB[12] = fmaf(wy, v3.x, accB[12]);
            accA[13] = fmaf(wx, v3.y, accA[13]); accB[13] = fmaf(wy, v3.y, accB[13]);
            accA[14] = fmaf(wx, v3.z, accA[14]); accB[14] = fmaf(wy, v3.z, accB[14]);
            accA[15] = fmaf(wx, v3.w, accA[15]); accB[15] = fmaf(wy, v3.w, accB[15]);
        }
    }

    // ---- cross-wave reduce: waves 2,3 write slots 0,1; waves 0,1 add in
    {
        float* rr = &red[((w & 1) * 64 + lane) * 33];
        if (w >= 2) {
            #pragma unroll
            for (int b = 0; b < 16; ++b) { rr[b] = accA[b]; rr[16 + b] = accB[b]; }
        }
        __syncthreads();
        if (w < 2) {
            #pragma unroll
            for (int b = 0; b < 16; ++b) { rr[b] += accA[b]; rr[16 + b] += accB[b]; }
        }
        __syncthreads();
    }

    // ---- epilogue: thread -> 8 cells (e_loc = t&127, b-oct = (t>>7)*8); RAW
    {
        const int e_loc = t & 127;
        const int b0    = (t >> 7) * 8;
        const int lane2 = e_loc >> 1;
        const int sub   = e_loc & 1;
        const int o0    = sub * 16 + b0;
        float s[8];
        #pragma unroll
        for (int j = 0; j < 8; ++j)
            s[j] = red[(0 * 64 + lane2) * 33 + o0 + j]
                 + red[(1 * 64 + lane2) * 33 + o0 + j];
        float* dst = slab + ((size_t)(n * 2 + dh)) * 4096
                   + (size_t)(e0 + e_loc) * 16 + b0;
        *(float4*)(dst + 0) = make_float4(s[0], s[1], s[2], s[3]);
        *(float4*)(dst + 4) = make_float4(s[4], s[5], s[6], s[7]);
    }
}

// NQ=2 reduce: 64 blocks x 256 thr, BRANCHLESS, tanh inside fired-mask.
// acct[c] = scale * sum_n fired[n]*tanh(slab[n][0][c]+slab[n][1][c]+bias[n][e])
template<bool IS_FINAL>
__global__ __launch_bounds__(256) void reduce_split(
    const float* __restrict__ slab, const float* __restrict__ biasl,
    const float* __restrict__ fired_l,
    float* __restrict__ acct, float* __restrict__ colsum,
    float* __restrict__ meta, float* __restrict__ out)
{
    __shared__ float part[256];
    __shared__ float shcnt;
    const int t    = threadIdx.x;
    const int cell = blockIdx.x * 64 + (t & 63);
    const int n0   = (t >> 6) * 32;
    const int e    = cell >> 4;

    float s = 0.0f;
    #pragma unroll 8
    for (int k = 0; k < 32; ++k) {
        const int n = n0 + k;
        const float p = slab[((size_t)(n * 2 + 0)) * 4096 + cell]
                      + slab[((size_t)(n * 2 + 1)) * 4096 + cell];
        s = fmaf(fired_l[n], tanhf(p + biasl[n * D + e]), s);
    }
    part[t] = s;

    if (t < 64) {
        float c = fired_l[t] + fired_l[t + 64];
        #pragma unroll
        for (int o = 32; o > 0; o >>= 1) c += __shfl_down(c, o);
        if (t == 0) shcnt = c;
    }
    __syncthreads();

    if (t < 64) {
        const float cnt = shcnt;
        const int c = blockIdx.x * 64 + t;
        const float tot = part[t] + part[64 + t] + part[128 + t] + part[192 + t];
        if (IS_FINAL) {
            out[(c & 15) * 256 + (c >> 4)] = tot / fmaxf(cnt, 1.0f);
        } else {
            const float scale = expf(-LAMBDA_ASYNC) / fmaxf(cnt, 1.0f);
            const float v = tot * scale;
            acct[c] = v;
            float cs = v;
            cs += __shfl_down(cs, 8);
            cs += __shfl_down(cs, 4);
            cs += __shfl_down(cs, 2);
            cs += __shfl_down(cs, 1);
            if ((t & 15) == 0) colsum[c >> 4] = cs;
            if (blockIdx.x == 0 && t == 0) meta[0] = cnt;
        }
    }
}

// ======== NQ=1 fallback: R15's proven kernels (verbatim) ========
__global__ __launch_bounds__(512) void layer_full(
    const float* __restrict__ Wl, const float* __restrict__ biasl,
    const float* __restrict__ Sl, const float* __restrict__ rhol,
    const float* __restrict__ boostl, const int* __restrict__ tb,
    const float* __restrict__ vin_src, const float* __restrict__ colsum,
    const float* __restrict__ meta_prev,
    float* __restrict__ slab, float* __restrict__ fired_cur,
    float depth, int is_first)
{
    __shared__ float vin[D * 16];
    __shared__ float red[4 * 64 * 33];
    __shared__ float sh[8];

    const int t    = threadIdx.x;
    const int w    = t >> 6;
    const int lane = t & 63;
    const int n    = blockIdx.x >> 1;
    const int e0   = (blockIdx.x & 1) * 128;

    float part = 0.0f;
    if (t < 256) part = colsum[t] * Sl[n * D + t];
    #pragma unroll
    for (int o = 32; o > 0; o >>= 1) part += __shfl_down(part, o);
    if (lane == 0) sh[w] = part;
    __syncthreads();
    {
        const bool has_input = is_first ? true : (meta_prev[0] > 0.0f);
        const float sdot = (sh[0] + sh[1] + sh[2] + sh[3]) * (1.0f / 16.0f);
        const float tau  = 0.5f * expf(LAMBDA_TAU * (depth - (float)tb[0]));
        const bool fired = (rhol[n] + sdot + boostl[n] >= tau) && has_input;
        if ((blockIdx.x & 1) == 0 && t == 0) fired_cur[n] = fired ? 1.0f : 0.0f;
        if (!fired) return;
    }
    {
        const float4* s4 = (const float4*)vin_src;
        ((float4*)vin)[t * 2 + 0] = s4[t * 2 + 0];
        ((float4*)vin)[t * 2 + 1] = s4[t * 2 + 1];
        __syncthreads();
    }

    const float* wp = Wl + (size_t)n * D * D + (e0 + lane * 2);
    const int dbase = w * 32;
    float accA[16], accB[16];
    #pragma unroll
    for (int b = 0; b < 16; ++b) { accA[b] = 0.0f; accB[b] = 0.0f; }
    #pragma unroll
    for (int j = 0; j < 32; j += 4) {
        float2 wv[4];
        #pragma unroll
        for (int i = 0; i < 4; ++i)
            wv[i] = *(const float2*)(wp + (size_t)(dbase + j + i) * 256);
        #pragma unroll
        for (int i = 0; i < 4; ++i) {
            const float* vr = &vin[(dbase + j + i) * 16];
            const float4 v0 = *(const float4*)(vr + 0);
            const float4 v1 = *(const float4*)(vr + 4);
            const float4 v2 = *(const float4*)(vr + 8);
            const float4 v3 = *(const float4*)(vr + 12);
            const float wx = wv[i].x, wy = wv[i].y;
            accA[ 0] = fmaf(wx, v0.x, accA[ 0]); accB[ 0] = fmaf(wy, v0.x, accB[ 0]);
            accA[ 1] = fmaf(wx, v0.y, accA[ 1]); accB[ 1] = fmaf(wy, v0.y, accB[ 1]);
            accA[ 2] = fmaf(wx, v0.z, accA[ 2]); accB[ 2] = fmaf(wy, v0.z, accB[ 2]);
            accA[ 3] = fmaf(wx, v0.w, accA[ 3]); accB[ 3] = fmaf(wy, v0.w, accB[ 3]);
            accA[ 4] = fmaf(wx, v1.x, accA[ 4]); accB[ 4] = fmaf(wy, v1.x, accB[ 4]);
            accA[ 5] = fmaf(wx, v1.y, accA[ 5]); accB[ 5] = fmaf(wy, v1.y, accB[ 5]);
            accA[ 6] = fmaf(wx, v1.z, accA[ 6]); accB[ 6] = fmaf(wy, v1.z, accB[ 6]);
            accA[ 7] = fmaf(wx, v1.w, accA[ 7]); accB[ 7] = fmaf(wy, v1.w, accB[ 7]);
            accA[ 8] = fmaf(wx, v2.x, accA[ 8]); accB[ 8] = fmaf(wy, v2.x, accB[ 8]);
            accA[ 9] = fmaf(wx, v2.y, accA[ 9]); accB[ 9] = fmaf(wy, v2.y, accB[ 9]);
            accA[10] = fmaf(wx, v2.z, accA[10]); accB[10] = fmaf(wy, v2.z, accB[10]);
            accA[11] = fmaf(wx, v2.w, accA[11]); accB[11] = fmaf(wy, v2.w, accB[11]);
            accA[12] = fmaf(wx, v3.x, accA[12]); accB[12] = fmaf(wy, v3.x, accB[12]);
            accA[13] = fmaf(wx, v3.y, accA[13]); accB[13] = fmaf(wy, v3.y, accB[13]);
            accA[14] = fmaf(wx, v3.z, accA[14]); accB[14] = fmaf(wy, v3.z, accB[14]);
            accA[15] = fmaf(wx, v3.w, accA[15]); accB[15] = fmaf(wy, v3.w, accB[15]);
        }
    }
    {
        float* rr = &red[((w & 3) * 64 + lane) * 33];
        if (w >= 4) {
            #pragma unroll
            for (int b = 0; b < 16; ++b) { rr[b] = accA[b]; rr[16 + b] = accB[b]; }
        }
        __syncthreads();
        if (w < 4) {
            #pragma unroll
            for (int b = 0; b < 16; ++b) { rr[b] += accA[b]; rr[16 + b] += accB[b]; }
        }
        __syncthreads();
    }
    {
        const int e_loc = t >> 2;
        const int b0    = (t & 3) * 4;
        const int lane2 = e_loc >> 1;
        const int sub   = e_loc & 1;
        const int o0    = sub * 16 + b0;
        const float bv  = biasl[n * D + e0 + e_loc];
        float4 o4;
        o4.x = tanhf(red[(0*64+lane2)*33 + o0+0] + red[(1*64+lane2)*33 + o0+0]
                   + red[(2*64+lane2)*33 + o0+0] + red[(3*64+lane2)*33 + o0+0] + bv);
        o4.y = tanhf(red[(0*64+lane2)*33 + o0+1] + red[(1*64+lane2)*33 + o0+1]
                   + red[(2*64+lane2)*33 + o0+1] + red[(3*64+lane2)*33 + o0+1] + bv);
        o4.z = tanhf(red[(0*64+lane2)*33 + o0+2] + red[(1*64+lane2)*33 + o0+2]
                   + red[(2*64+lane2)*33 + o0+2] + red[(3*64+lane2)*33 + o0+2] + bv);
        o4.w = tanhf(red[(0*64+lane2)*33 + o0+3] + red[(1*64+lane2)*33 + o0+3]
                   + red[(2*64+lane2)*33 + o0+3] + red[(3*64+lane2)*33 + o0+3] + bv);
        *(float4*)(slab + (size_t)n * 4096 + (size_t)(e0 + e_loc) * 16 + b0) = o4;
    }
}

template<bool IS_FINAL>
__global__ __launch_bounds__(256) void reduce_full(
    const float* __restrict__ slab, const float* __restrict__ fired_l,
    float* __restrict__ acct, float* __restrict__ colsum,
    float* __restrict__ meta, float* __restrict__ out)
{
    __shared__ float part[256];
    __shared__ float shcnt;
    const int t    = threadIdx.x;
    const int cell = blockIdx.x * 64 + (t & 63);
    const int n0   = (t >> 6) * 32;

    float s = 0.0f;
    #pragma unroll 8
    for (int k = 0; k < 32; ++k)
        s = fmaf(fired_l[n0 + k], slab[(size_t)(n0 + k) * 4096 + cell], s);
    part[t] = s;

    if (t < 64) {
        float c = fired_l[t] + fired_l[t + 64];
        #pragma unroll
        for (int o = 32; o > 0; o >>= 1) c += __shfl_down(c, o);
        if (t == 0) shcnt = c;
    }
    __syncthreads();

    if (t < 64) {
        const float cnt = shcnt;
        const int c = blockIdx.x * 64 + t;
        const float tot = part[t] + part[64 + t] + part[128 + t] + part[192 + t];
        if (IS_FINAL) {
            out[(c & 15) * 256 + (c >> 4)] = tot / fmaxf(cnt, 1.0f);
        } else {
            const float scale = expf(-LAMBDA_ASYNC) / fmaxf(cnt, 1.0f);
            const float v = tot * scale;
            acct[c] = v;
            float cs = v;
            cs += __shfl_down(cs, 8);
            cs += __shfl_down(cs, 4);
            cs += __shfl_down(cs, 2);
            cs += __shfl_down(cs, 1);
            if ((t & 15) == 0) colsum[c >> 4] = cs;
            if (blockIdx.x == 0 && t == 0) meta[0] = cnt;
        }
    }
}

extern "C" void kernel_launch(void* const* d_in, const int* in_sizes, int n_in,
                              void* d_out, int out_size, void* d_ws, size_t ws_size,
                              hipStream_t stream)
{
    const float* X     = (const float*)d_in[0];
    const float* W     = (const float*)d_in[1];
    const float* bias  = (const float*)d_in[2];
    const float* S     = (const float*)d_in[3];
    const float* rho   = (const float*)d_in[4];
    const float* boost = (const float*)d_in[5];
    const int*   tb    = (const int*)d_in[6];
    float* out = (float*)d_out;
    float* ws  = (float*)d_ws;

    float* acct   = ws;
    float* colsum = ws + OFF_COLSUM;
    float* meta   = ws + OFF_META;
    float* fired  = ws + OFF_FIRED;
    float* slab   = ws + OFF_SLAB;

    const bool split = ws_size >= (size_t)(OFF_SLAB + N * 2 * 4096) * sizeof(float);

    // xt reuses acct slot (layer 0 stages from it before reduce 0 overwrites)
    transpose_kernel<<<dim3(1), dim3(256), 0, stream>>>(X, acct, colsum);

    for (int l = 0; l < L; ++l) {
        const float* Wl = W + (size_t)l * N * D * D;
        const float* bl = bias + (size_t)l * N * D;
        const float* Sl = S + (size_t)l * N * D;
        const float* rl = rho + (size_t)l * N;
        const float* gl = boost + (size_t)l * N;
        const float* mp = (l == 0) ? (const float*)nullptr : meta;
        const float dep = (float)(l + 1);
        const int first = (l == 0) ? 1 : 0;

        if (split) {
            layer_split<<<dim3(N * 4), dim3(256), 0, stream>>>(
                Wl, Sl, rl, gl, tb, acct, colsum, mp, slab, fired, dep, first);
            if (l < L - 1)
                reduce_split<false><<<dim3(64), dim3(256), 0, stream>>>(
                    slab, bl, fired, acct, colsum, meta, out);
            else
                reduce_split<true><<<dim3(64), dim3(256), 0, stream>>>(
                    slab, bl, fired, acct, colsum, meta, out);
        } else {
            layer_full<<<dim3(N * 2), dim3(512), 0, stream>>>(
                Wl, bl, Sl, rl, gl, tb, acct, colsum, mp, slab, fired, dep, first);
            if (l < L - 1)
                reduce_full<false><<<dim3(64), dim3(256), 0, stream>>>(
                    slab, fired, acct, colsum, meta, out);
            else
                reduce_full<true><<<dim3(64), dim3(256), 0, stream>>>(
                    slab, fired, acct, colsum, meta, out);
        }
    }
}